// Round 9
// baseline (1504.921 us; speedup 1.0000x reference)
//
#include <hip/hip_runtime.h>

#define HD 64
#define BN_EPS 1e-5f
#define NT 256

typedef __attribute__((ext_vector_type(8))) short bfrag;
typedef __attribute__((ext_vector_type(4))) float ffrag;

__device__ __forceinline__ unsigned tobf(float x) {
    unsigned u = __float_as_uint(x);
    return (u + 0x7fffu + ((u >> 16) & 1u)) >> 16;
}
__device__ __forceinline__ float bf_lo(unsigned u) { return __uint_as_float(u << 16); }
__device__ __forceinline__ float bf_hi(unsigned u) { return __uint_as_float(u & 0xffff0000u); }

struct Params {
    const float* x;
    const int* srcA;
    const int* dstA;
    const int* batch;
    const float* W0; const float* b0; const float* g0; const float* be0;
    const float* W1; const float* b1; const float* g1; const float* be1;
    const float* W2; const float* b2; const float* g2; const float* be2;
    int* deg; int* cur; float* stats; int* wctr; int* tick; float* praw;  // zero-region
    float* dinv; int* rowp; int* bsums; int* ed;
    unsigned short* hWs; unsigned short* hraw;
    float* ss; unsigned* Wfb; float* cf; int* gcnt;
    int* bars;
    float* pool; float* hbuf;
    int N, E, G, zcnt;
};

// device-scope grid barrier; assumes all blocks co-resident (grid sized by
// occupancy API). Timeout makes a broken assumption terminate, not hang.
__device__ __forceinline__ void gridbar(int* b, int nb) {
    __syncthreads();
    if (threadIdx.x == 0) {
        __hip_atomic_fetch_add(b, 1, __ATOMIC_RELEASE, __HIP_MEMORY_SCOPE_AGENT);
        long long t0 = clock64();
        while (__hip_atomic_load(b, __ATOMIC_RELAXED, __HIP_MEMORY_SCOPE_AGENT) < nb) {
            __builtin_amdgcn_s_sleep(16);
            if (clock64() - t0 > 30000000LL) break;  // ~12 ms safety valve
        }
    }
    __syncthreads();
    __threadfence();   // acquire: invalidate caches so cross-XCD writes are visible
}

__global__ __launch_bounds__(NT, 4) void mega(Params p) {
    const int tid = threadIdx.x;
    const int nb = gridDim.x;
    const int gsz = nb * NT;
    const int nwave = nb * 4;
    const int gtid = blockIdx.x * NT + tid;
    const int lane = tid & 63;
    const int hf = lane >> 5;
    const int m = lane & 31;
    const int wid = gtid >> 6;
    const int N = p.N, E = p.E, G = p.G;

    __shared__ int ish[NT];
    __shared__ float r1s[4][HD];
    __shared__ float r2s[4][HD];

    // ---- P0: zero workspace region + hWs zero-row ----
    {
        int* zb = p.deg;
        for (int i = gtid; i < p.zcnt; i += gsz) zb[i] = 0;
        unsigned* hw = (unsigned*)p.hWs;
        if (gtid < 32) hw[(size_t)N * 32 + gtid] = 0u;
    }
    gridbar(p.bars + 0, nb);

    // ---- P1: degree count ----
    for (int e = gtid; e < E; e += gsz) atomicAdd(&p.deg[p.dstA[e]], 1);
    gridbar(p.bars + 1, nb);

    // ---- P2a: per-block local scan of padded degree over its chunk ----
    const int CH = (N + nb - 1) / nb;
    const int nb0 = blockIdx.x * CH;
    const int cend = min(CH, N - nb0);   // may be <= 0
    {
        int carry = 0;
        for (int t0 = 0; t0 < cend; t0 += NT) {
            int i = nb0 + t0 + tid;
            bool valid = (t0 + tid) < cend;
            int d = valid ? p.deg[i] : 0;
            int pd = valid ? ((d + 16) & ~15) : 0;
            __syncthreads();
            ish[tid] = pd;
            __syncthreads();
            for (int off = 1; off < NT; off <<= 1) {
                int t = (tid >= off) ? ish[tid - off] : 0;
                __syncthreads();
                ish[tid] += t;
                __syncthreads();
            }
            if (valid) {
                p.rowp[i] = carry + ish[tid] - pd;   // block-local exclusive
                p.dinv[i] = rsqrtf((float)(d + 1));
            }
            carry += ish[NT - 1];
        }
        if (tid == 0) p.bsums[blockIdx.x] = carry;
    }
    gridbar(p.bars + 2, nb);

    // ---- P2b: block prefix of bsums + globalize rowp + self/pad slots ----
    {
        int ps = 0;
        for (int t = tid; t < (int)blockIdx.x; t += NT) ps += p.bsums[t];
        __syncthreads();
        ish[tid] = ps;
        __syncthreads();
        for (int off = NT / 2; off > 0; off >>= 1) {
            if (tid < off) ish[tid] += ish[tid + off];
            __syncthreads();
        }
        int bpre = ish[0];
        for (int t0 = tid; t0 < cend; t0 += NT) {
            int i = nb0 + t0;
            int d = p.deg[i];
            int pd = (d + 16) & ~15;
            int rv = p.rowp[i] + bpre;
            p.rowp[i] = rv;
            p.ed[rv] = i;                                   // self edge slot 0
            for (int k = d + 1; k < pd; k++) p.ed[rv + k] = N;  // pads -> zero row
            if (i == N - 1) p.rowp[N] = rv + pd;
        }
    }
    gridbar(p.bars + 3, nb);

    const int ntiles = (N + 15) >> 4;
    const unsigned* hWsU = (const unsigned*)p.hWs;

    // ---- P3: bucket edges + per-graph counts + gemm layer 0 (independent) ----
    for (int e = gtid; e < E; e += gsz) {
        int dd = p.dstA[e];
        int pos = p.rowp[dd] + 1 + atomicAdd(&p.cur[dd], 1);
        p.ed[pos] = p.srcA[e];
    }
    for (int g = gtid; g < G; g += gsz) {
        int lo = 0, hi = N;
        while (lo < hi) { int mid = (lo + hi) >> 1; if (p.batch[mid] < g) lo = mid + 1; else hi = mid; }
        int lo2 = lo, hi2 = N;
        while (lo2 < hi2) { int mid = (lo2 + hi2) >> 1; if (p.batch[mid] < g + 1) lo2 = mid + 1; else hi2 = mid; }
        p.gcnt[g] = lo2 - lo;
    }
    {   // gemm l=0: hWs = bf16(dinv * (x @ W0^T))
        int mm = lane & 15, quad = lane >> 4;
        bfrag wf[4][2];
#pragma unroll
        for (int ft = 0; ft < 4; ft++)
#pragma unroll
            for (int kf = 0; kf < 2; kf++) {
                const float4* p4 = (const float4*)(p.W0 + (ft * 16 + mm) * HD + kf * 32 + quad * 8);
                float4 x0 = p4[0], x1 = p4[1];
                union { unsigned u[4]; bfrag b; } r;
                r.u[0] = tobf(x0.x) | (tobf(x0.y) << 16);
                r.u[1] = tobf(x0.z) | (tobf(x0.w) << 16);
                r.u[2] = tobf(x1.x) | (tobf(x1.y) << 16);
                r.u[3] = tobf(x1.z) | (tobf(x1.w) << 16);
                wf[ft][kf] = r.b;
            }
        for (int tile = wid; tile < ntiles; tile += nwave) {
            int arow = min(tile * 16 + mm, N - 1);
            const float4* p4 = (const float4*)(p.x + (size_t)arow * HD + quad * 8);
            float4 x0 = p4[0], x1 = p4[1], y0 = p4[8], y1 = p4[9];
            union { unsigned u[4]; bfrag b; } r0, r1;
            r0.u[0] = tobf(x0.x) | (tobf(x0.y) << 16);
            r0.u[1] = tobf(x0.z) | (tobf(x0.w) << 16);
            r0.u[2] = tobf(x1.x) | (tobf(x1.y) << 16);
            r0.u[3] = tobf(x1.z) | (tobf(x1.w) << 16);
            r1.u[0] = tobf(y0.x) | (tobf(y0.y) << 16);
            r1.u[1] = tobf(y0.z) | (tobf(y0.w) << 16);
            r1.u[2] = tobf(y1.x) | (tobf(y1.y) << 16);
            r1.u[3] = tobf(y1.z) | (tobf(y1.w) << 16);
            bfrag a0 = r0.b, a1 = r1.b;
            ffrag acc[4];
#pragma unroll
            for (int ft = 0; ft < 4; ft++) {
                acc[ft] = (ffrag){0.f, 0.f, 0.f, 0.f};
                acc[ft] = __builtin_amdgcn_mfma_f32_16x16x32_bf16(a0, wf[ft][0], acc[ft], 0, 0, 0);
                acc[ft] = __builtin_amdgcn_mfma_f32_16x16x32_bf16(a1, wf[ft][1], acc[ft], 0, 0, 0);
            }
            int r0n = tile * 16 + quad * 4;
            float dv[4];
#pragma unroll
            for (int r = 0; r < 4; r++) dv[r] = p.dinv[min(r0n + r, N - 1)];
#pragma unroll
            for (int ft = 0; ft < 4; ft++)
#pragma unroll
                for (int r = 0; r < 4; r++) {
                    int nrow = r0n + r;
                    if (nrow < N)
                        p.hWs[(size_t)nrow * HD + ft * 16 + mm] =
                            (unsigned short)tobf(acc[ft][r] * dv[r]);
                }
        }
    }
    gridbar(p.bars + 4, nb);

    for (int l = 0; l < 3; l++) {
        const float* bias_l = (l == 0) ? p.b0 : (l == 1) ? p.b1 : p.b2;
        const float* gam_l  = (l == 0) ? p.g0 : (l == 1) ? p.g1 : p.g2;
        const float* bet_l  = (l == 0) ? p.be0 : (l == 1) ? p.be1 : p.be2;
        const float* Wnext  = (l == 0) ? p.W1 : (l == 1) ? p.W2 : nullptr;
        float* ss_l = p.ss + l * 128;
        float* praw_l = p.praw + (size_t)l * G * HD;
        float* stats_l = p.stats + l * 128;

        // ---- agg phase: work-stealing 8-node chunks, R5 inner loop ----
        {
            float b0v = bias_l[2 * m], b1v = bias_l[2 * m + 1];
            float bs0 = 0.f, bs1 = 0.f, bq0 = 0.f, bq1 = 0.f;
            int nchunk = (N + 7) >> 3;
            while (true) {
                int c = 0;
                if (lane == 0) c = atomicAdd(&p.wctr[l], 1);
                c = __shfl(c, 0);
                if (c >= nchunk) break;
                int i0c = c << 3;
                int i1c = min(i0c + 8, N);
                int curb = -1;
                float p0 = 0.f, p1 = 0.f;
                int sb = p.rowp[i0c];
                int send = p.rowp[i1c];
                int i = i0c;
                int rem = (p.rowp[i0c + 1] - sb) >> 4;
                float acc0 = 0.f, acc1 = 0.f;
                for (; sb < send; sb += 64) {
                    int eidx = p.ed[sb + lane];
                    int ng = min(4, (send - sb) >> 4);
                    for (int g = 0; g < ng; g++) {
                        unsigned u[8];
#pragma unroll
                        for (int jj = 0; jj < 8; jj++) {
                            int s = __shfl(eidx, (g << 4) + 2 * jj + hf);
                            u[jj] = hWsU[(size_t)s * 32 + m];
                        }
#pragma unroll
                        for (int jj = 0; jj < 8; jj++) {
                            acc0 += bf_lo(u[jj]);
                            acc1 += bf_hi(u[jj]);
                        }
                        if (--rem == 0) {  // node i complete (wave-uniform)
                            float s0 = acc0 + __shfl_xor(acc0, 32);
                            float s1 = acc1 + __shfl_xor(acc1, 32);
                            float di = p.dinv[i];
                            float h0 = fmaxf(fmaf(di, s0, b0v), 0.f);
                            float h1 = fmaxf(fmaf(di, s1, b1v), 0.f);
                            int b = p.batch[i];
                            if (lane < 32) {
                                if (l < 2) ((unsigned*)p.hraw)[(size_t)i * 32 + m] = tobf(h0) | (tobf(h1) << 16);
                                else ((float2*)p.hbuf)[(size_t)i * 32 + m] = make_float2(h0, h1);
                                bs0 += h0; bs1 += h1;
                                bq0 = fmaf(h0, h0, bq0); bq1 = fmaf(h1, h1, bq1);
                                if (b != curb) {
                                    if (curb >= 0) {
                                        atomicAdd(&praw_l[(size_t)curb * HD + 2 * m], p0);
                                        atomicAdd(&praw_l[(size_t)curb * HD + 2 * m + 1], p1);
                                    }
                                    curb = b; p0 = h0; p1 = h1;
                                } else { p0 += h0; p1 += h1; }
                            }
                            i++;
                            rem = (i < i1c) ? ((p.rowp[i + 1] - p.rowp[i]) >> 4) : 0x3fffffff;
                            acc0 = 0.f; acc1 = 0.f;
                        }
                    }
                }
                if (lane < 32 && curb >= 0) {
                    atomicAdd(&praw_l[(size_t)curb * HD + 2 * m], p0);
                    atomicAdd(&praw_l[(size_t)curb * HD + 2 * m + 1], p1);
                }
            }
            int wv = tid >> 6;
            __syncthreads();
            if (lane < 32) {
                r1s[wv][2 * m] = bs0; r1s[wv][2 * m + 1] = bs1;
                r2s[wv][2 * m] = bq0; r2s[wv][2 * m + 1] = bq1;
            }
            __syncthreads();
            if (tid < HD) {
                atomicAdd(&stats_l[tid], r1s[0][tid] + r1s[1][tid] + r1s[2][tid] + r1s[3][tid]);
                atomicAdd(&stats_l[HD + tid], r2s[0][tid] + r2s[1][tid] + r2s[2][tid] + r2s[3][tid]);
            }
            // last-done block computes BN affine + folds into next layer's W
            __shared__ int lastFlag;
            __syncthreads();
            if (tid == 0) {
                __threadfence();
                lastFlag = (__hip_atomic_fetch_add(&p.tick[l], 1, __ATOMIC_ACQ_REL,
                                                   __HIP_MEMORY_SCOPE_AGENT) == nb - 1) ? 1 : 0;
            }
            __syncthreads();
            if (lastFlag) {
                float* lss = (float*)r1s;  // 128 floats scratch
                if (tid < HD) {
                    float s1v = atomicAdd(&stats_l[tid], 0.f);
                    float s2v = atomicAdd(&stats_l[HD + tid], 0.f);
                    float invN = 1.0f / (float)N;
                    float mean = s1v * invN;
                    float var = s2v * invN - mean * mean;
                    float sc = gam_l[tid] * rsqrtf(var + BN_EPS);
                    float sh = bet_l[tid] - mean * sc;
                    ss_l[tid] = sc; ss_l[64 + tid] = sh;
                    lss[tid] = sc; lss[64 + tid] = sh;
                }
                __syncthreads();
                if (Wnext && tid < HD) {
                    unsigned* Wfb_l = p.Wfb + (size_t)l * HD * 32;
                    float c = 0.f;
                    for (int qq = 0; qq < 32; qq++) {
                        float wa = Wnext[tid * HD + 2 * qq];
                        float wb = Wnext[tid * HD + 2 * qq + 1];
                        Wfb_l[tid * 32 + qq] = tobf(wa * lss[2 * qq]) | (tobf(wb * lss[2 * qq + 1]) << 16);
                        c = fmaf(lss[64 + 2 * qq], wa, c);
                        c = fmaf(lss[64 + 2 * qq + 1], wb, c);
                    }
                    p.cf[l * HD + tid] = c;
                }
            }
        }
        gridbar(p.bars + 5 + 2 * l, nb);

        // ---- gemm l+1 (bf16 folded weights) ----
        if (l < 2) {
            int mm = lane & 15, quad = lane >> 4;
            const unsigned short* Wb = (const unsigned short*)(p.Wfb + (size_t)l * HD * 32);
            const float* cb = p.cf + l * HD;
            bfrag wf[4][2];
            float cbv[4];
#pragma unroll
            for (int ft = 0; ft < 4; ft++) {
#pragma unroll
                for (int kf = 0; kf < 2; kf++)
                    wf[ft][kf] = *(const bfrag*)(Wb + (ft * 16 + mm) * HD + kf * 32 + quad * 8);
                cbv[ft] = cb[ft * 16 + mm];
            }
            for (int tile = wid; tile < ntiles; tile += nwave) {
                int arow = min(tile * 16 + mm, N - 1);
                const unsigned short* pa = p.hraw + (size_t)arow * HD + quad * 8;
                bfrag a0 = *(const bfrag*)pa;
                bfrag a1 = *(const bfrag*)(pa + 32);
                ffrag acc[4];
#pragma unroll
                for (int ft = 0; ft < 4; ft++) {
                    acc[ft] = (ffrag){0.f, 0.f, 0.f, 0.f};
                    acc[ft] = __builtin_amdgcn_mfma_f32_16x16x32_bf16(a0, wf[ft][0], acc[ft], 0, 0, 0);
                    acc[ft] = __builtin_amdgcn_mfma_f32_16x16x32_bf16(a1, wf[ft][1], acc[ft], 0, 0, 0);
                }
                int r0n = tile * 16 + quad * 4;
                float dv[4];
#pragma unroll
                for (int r = 0; r < 4; r++) dv[r] = p.dinv[min(r0n + r, N - 1)];
#pragma unroll
                for (int ft = 0; ft < 4; ft++)
#pragma unroll
                    for (int r = 0; r < 4; r++) {
                        int nrow = r0n + r;
                        if (nrow < N)
                            p.hWs[(size_t)nrow * HD + ft * 16 + mm] =
                                (unsigned short)tobf((acc[ft][r] + cbv[ft]) * dv[r]);
                    }
            }
            gridbar(p.bars + 6 + 2 * l, nb);
        }
    }

    // ---- fin: normalize final h in place + pool finalize ----
    {
        const float* ssf = p.ss + 2 * 128;
        int nquads = N * HD / 4;
        float4* h4 = (float4*)p.hbuf;
        for (int idx = gtid; idx < nquads; idx += gsz) {
            float4 v = h4[idx];
            int f0 = (idx * 4) & 63;
            v.x = fmaf(v.x, ssf[f0 + 0], ssf[64 + f0 + 0]);
            v.y = fmaf(v.y, ssf[f0 + 1], ssf[64 + f0 + 1]);
            v.z = fmaf(v.z, ssf[f0 + 2], ssf[64 + f0 + 2]);
            v.w = fmaf(v.w, ssf[f0 + 3], ssf[64 + f0 + 3]);
            h4[idx] = v;
        }
        for (int idx = gtid; idx < G * 192; idx += gsz) {
            int g = idx / 192;
            int r = idx - g * 192;
            int ll = r >> 6;
            int f = r & 63;
            const float* ssl = p.ss + ll * 128;
            float v = p.praw[((size_t)ll * G + g) * HD + f];
            p.pool[idx] = fmaf(ssl[f], v, (float)p.gcnt[g] * ssl[64 + f]);
        }
    }
}

extern "C" void kernel_launch(void* const* d_in, const int* in_sizes, int n_in,
                              void* d_out, int out_size, void* d_ws, size_t ws_size,
                              hipStream_t stream) {
    const int N = in_sizes[0] / HD;             // 100000
    const int E = in_sizes[1] / 2;              // 1000000
    const int G = (out_size - N * HD) / 192;    // 512

    char* ws = (char*)d_ws;
    size_t off = 0;
    auto alloc = [&](size_t bytes) -> void* {
        void* pp = ws + off;
        off = (off + bytes + 255) & ~(size_t)255;
        return pp;
    };
    int* bars    = (int*)alloc(16 * 4);           // zeroed by memset each call
    // zero-region (P0): deg, cur, stats, wctr, tick, praw
    int* deg     = (int*)alloc((size_t)N * 4);
    int* cur     = (int*)alloc((size_t)N * 4);
    float* stats = (float*)alloc(3 * 128 * 4);
    int* wctr    = (int*)alloc(3 * 4);
    int* tick    = (int*)alloc(3 * 4);
    float* praw  = (float*)alloc((size_t)3 * G * HD * 4);
    size_t zend = off;
    float* dinv  = (float*)alloc((size_t)N * 4);
    int* rowp    = (int*)alloc((size_t)(N + 1) * 4);
    int* bsums   = (int*)alloc(1024 * 4);
    int* ed      = (int*)alloc(((size_t)E + 16 * (size_t)N + 128) * 4);
    unsigned short* hWs  = (unsigned short*)alloc((size_t)(N + 1) * HD * 2);
    unsigned short* hraw = (unsigned short*)alloc((size_t)N * HD * 2);
    float* ss    = (float*)alloc(3 * 128 * 4);
    unsigned* Wfb = (unsigned*)alloc(2 * HD * 32 * 4);
    float* cf    = (float*)alloc(2 * HD * 4);
    int* gcnt    = (int*)alloc((size_t)G * 4);
    (void)ws_size;

    Params prm;
    prm.x = (const float*)d_in[0];
    prm.srcA = (const int*)d_in[1];
    prm.dstA = (const int*)d_in[1] + E;
    prm.batch = (const int*)d_in[2];
    prm.W0 = (const float*)d_in[3];  prm.b0 = (const float*)d_in[4];
    prm.g0 = (const float*)d_in[5];  prm.be0 = (const float*)d_in[6];
    prm.W1 = (const float*)d_in[7];  prm.b1 = (const float*)d_in[8];
    prm.g1 = (const float*)d_in[9];  prm.be1 = (const float*)d_in[10];
    prm.W2 = (const float*)d_in[11]; prm.b2 = (const float*)d_in[12];
    prm.g2 = (const float*)d_in[13]; prm.be2 = (const float*)d_in[14];
    prm.deg = deg; prm.cur = cur; prm.stats = stats; prm.wctr = wctr;
    prm.tick = tick; prm.praw = praw;
    prm.dinv = dinv; prm.rowp = rowp; prm.bsums = bsums; prm.ed = ed;
    prm.hWs = hWs; prm.hraw = hraw; prm.ss = ss; prm.Wfb = Wfb; prm.cf = cf;
    prm.gcnt = gcnt; prm.bars = bars;
    prm.pool = (float*)d_out;
    prm.hbuf = (float*)d_out + (size_t)G * 192;
    prm.N = N; prm.E = E; prm.G = G;
    prm.zcnt = (int)((zend - ((char*)deg - ws)) / 4);

    // size grid so ALL blocks are co-resident (barriers require it)
    int nbpc = 0;
    hipError_t oe = hipOccupancyMaxActiveBlocksPerMultiprocessor(&nbpc, (const void*)mega, NT, 0);
    if (oe != hipSuccess || nbpc < 1) nbpc = 1;
    int NB = nbpc * 256;          // 256 CUs on MI355X
    if (NB > 1024) NB = 1024;

    hipMemsetAsync(bars, 0, 16 * 4, stream);
    mega<<<NB, NT, 0, stream>>>(prm);
}

// Round 10
// 552.295 us; speedup vs baseline: 2.7249x; 2.7249x over previous
//
#include <hip/hip_runtime.h>

#define HD 64
#define BN_EPS 1e-5f
#define NWAVES 8192

typedef __attribute__((ext_vector_type(8))) short bfrag;
typedef __attribute__((ext_vector_type(4))) float ffrag;

__device__ __forceinline__ unsigned tobf(float x) {
    unsigned u = __float_as_uint(x);
    return (u + 0x7fffu + ((u >> 16) & 1u)) >> 16;
}
__device__ __forceinline__ float bf_lo(unsigned u) { return __uint_as_float(u << 16); }
__device__ __forceinline__ float bf_hi(unsigned u) { return __uint_as_float(u & 0xffff0000u); }

// ---------- CSR construction (rows padded to 16: slot0=self, pads->node N) ----------

__global__ void k_deg(const int* __restrict__ dst, int* __restrict__ deg, int E) {
    int e = blockIdx.x * blockDim.x + threadIdx.x;
    if (e < E) atomicAdd(&deg[dst[e]], 1);
}

// inclusive scan of padded degree (256/block) + dinv + hWs zero-row init
__global__ void k_scan1(const int* __restrict__ deg, int* __restrict__ incl,
                        int* __restrict__ bsums, float* __restrict__ dinv,
                        unsigned* __restrict__ hWs, int N) {
    __shared__ int s[256];
    int tid = threadIdx.x;
    int i = blockIdx.x * 256 + tid;
    if (blockIdx.x == 0 && tid < 32) hWs[(size_t)N * 32 + tid] = 0u;  // zero row
    int d = (i < N) ? deg[i] : 0;
    int pd = (i < N) ? ((d + 16) & ~15) : 0;  // roundup(deg+1, 16)
    s[tid] = pd;
    __syncthreads();
    for (int off = 1; off < 256; off <<= 1) {
        int t = (tid >= off) ? s[tid - off] : 0;
        __syncthreads();
        s[tid] += t;
        __syncthreads();
    }
    if (i < N) {
        incl[i] = s[tid];
        dinv[i] = rsqrtf((float)(d + 1));
    }
    if (tid == 255) bsums[blockIdx.x] = s[255];
}

// rowp from incl + per-block prefix of bsums; self edge in slot0, pads -> N
__global__ void k_scan3(int* __restrict__ rowp, const int* __restrict__ deg,
                        const int* __restrict__ incl, const int* __restrict__ bsums,
                        int* __restrict__ ed, int N, int nb) {
    __shared__ float red[256];
    int tid = threadIdx.x;
    int b = blockIdx.x;
    float psum = 0.f;
    for (int t = tid; t < b; t += 256) psum += (float)bsums[t];
    red[tid] = psum;
    __syncthreads();
    for (int off = 128; off > 0; off >>= 1) {
        if (tid < off) red[tid] += red[tid + off];
        __syncthreads();
    }
    int bpre = (int)red[0];
    int i = b * 256 + tid;
    if (i < N) {
        int d = deg[i];
        int pd = (d + 16) & ~15;
        int rv = incl[i] - pd + bpre;  // exclusive global offset
        rowp[i] = rv;
        ed[rv] = i;  // self edge in slot 0
        for (int k = d + 1; k < pd; k++) ed[rv + k] = N;  // pads -> zero row
        if (i == N - 1) rowp[N] = rv + pd;
    }
}

// bucket edges into CSR slots (offset by 1 for self) + per-graph counts fused
__global__ void k_fill(const int* __restrict__ src, const int* __restrict__ dst,
                       const int* __restrict__ rowp, int* __restrict__ cur,
                       int* __restrict__ ed, const int* __restrict__ batch,
                       int* __restrict__ cnt, int E, int N, int G) {
    int e = blockIdx.x * blockDim.x + threadIdx.x;
    if (e < G) {
        int g = e;
        int lo = 0, hi = N;
        while (lo < hi) { int mid = (lo + hi) >> 1; if (batch[mid] < g) lo = mid + 1; else hi = mid; }
        int lo2 = lo, hi2 = N;
        while (lo2 < hi2) { int mid = (lo2 + hi2) >> 1; if (batch[mid] < g + 1) lo2 = mid + 1; else hi2 = mid; }
        cnt[g] = lo2 - lo;
    }
    if (e >= E) return;
    int d = dst[e];
    int pos = rowp[d] + 1 + atomicAdd(&cur[d], 1);
    ed[pos] = src[e];
}

// ---------- MFMA gemm: hWs[i][f] = bf16( dinv[i]*(sum_k A[i][k]*W[f][k] + cb[f]) ) ----------
template<int FP32IN>
__global__ __launch_bounds__(256) void k_gemm2(const void* __restrict__ Aptr,
                                               const void* __restrict__ Wptr,
                                               const float* __restrict__ cb,
                                               const float* __restrict__ dinv,
                                               unsigned short* __restrict__ hWs,
                                               int N, int ntiles) {
    int lane = threadIdx.x & 63;
    int m = lane & 15, quad = lane >> 4;
    bfrag wf[4][2];
    if (FP32IN) {
        const float* W = (const float*)Wptr;
#pragma unroll
        for (int ft = 0; ft < 4; ft++)
#pragma unroll
            for (int kf = 0; kf < 2; kf++) {
                const float4* p4 = (const float4*)(W + (ft * 16 + m) * HD + kf * 32 + quad * 8);
                float4 x0 = p4[0], x1 = p4[1];
                union { unsigned u[4]; bfrag b; } r;
                r.u[0] = tobf(x0.x) | (tobf(x0.y) << 16);
                r.u[1] = tobf(x0.z) | (tobf(x0.w) << 16);
                r.u[2] = tobf(x1.x) | (tobf(x1.y) << 16);
                r.u[3] = tobf(x1.z) | (tobf(x1.w) << 16);
                wf[ft][kf] = r.b;
            }
    } else {
        const unsigned short* W = (const unsigned short*)Wptr;
#pragma unroll
        for (int ft = 0; ft < 4; ft++)
#pragma unroll
            for (int kf = 0; kf < 2; kf++)
                wf[ft][kf] = *(const bfrag*)(W + (ft * 16 + m) * HD + kf * 32 + quad * 8);
    }
    float cbv[4];
#pragma unroll
    for (int ft = 0; ft < 4; ft++) cbv[ft] = cb ? cb[ft * 16 + m] : 0.f;

    int wid = (blockIdx.x * blockDim.x + threadIdx.x) >> 6;
    int nw = (gridDim.x * blockDim.x) >> 6;
    for (int tile = wid; tile < ntiles; tile += nw) {
        int arow = min(tile * 16 + m, N - 1);
        bfrag a0, a1;
        if (FP32IN) {
            const float4* p4 = (const float4*)((const float*)Aptr + (size_t)arow * HD + quad * 8);
            float4 x0 = p4[0], x1 = p4[1], y0 = p4[8], y1 = p4[9];
            union { unsigned u[4]; bfrag b; } r0, r1;
            r0.u[0] = tobf(x0.x) | (tobf(x0.y) << 16);
            r0.u[1] = tobf(x0.z) | (tobf(x0.w) << 16);
            r0.u[2] = tobf(x1.x) | (tobf(x1.y) << 16);
            r0.u[3] = tobf(x1.z) | (tobf(x1.w) << 16);
            r1.u[0] = tobf(y0.x) | (tobf(y0.y) << 16);
            r1.u[1] = tobf(y0.z) | (tobf(y0.w) << 16);
            r1.u[2] = tobf(y1.x) | (tobf(y1.y) << 16);
            r1.u[3] = tobf(y1.z) | (tobf(y1.w) << 16);
            a0 = r0.b; a1 = r1.b;
        } else {
            const unsigned short* p = (const unsigned short*)Aptr + (size_t)arow * HD + quad * 8;
            a0 = *(const bfrag*)p;
            a1 = *(const bfrag*)(p + 32);
        }
        ffrag acc[4];
#pragma unroll
        for (int ft = 0; ft < 4; ft++) {
            acc[ft] = (ffrag){0.f, 0.f, 0.f, 0.f};
            acc[ft] = __builtin_amdgcn_mfma_f32_16x16x32_bf16(a0, wf[ft][0], acc[ft], 0, 0, 0);
            acc[ft] = __builtin_amdgcn_mfma_f32_16x16x32_bf16(a1, wf[ft][1], acc[ft], 0, 0, 0);
        }
        int r0n = tile * 16 + quad * 4;
        float dv[4];
#pragma unroll
        for (int r = 0; r < 4; r++) dv[r] = dinv[min(r0n + r, N - 1)];
#pragma unroll
        for (int ft = 0; ft < 4; ft++)
#pragma unroll
            for (int r = 0; r < 4; r++) {
                int nrow = r0n + r;
                if (nrow < N) {
                    float v = (acc[ft][r] + cbv[ft]) * dv[r];
                    hWs[(size_t)nrow * HD + ft * 16 + m] = (unsigned short)tobf(v);
                }
            }
    }
}

// ---------- aggregation: R5 structure + deep-issue full stages (32 gathers in
// flight per 64-slot stage). Last block does BN finalize + weight fold. ----------
__global__ __launch_bounds__(256) void k_agg(const int* __restrict__ rowp,
                                             const int* __restrict__ ed,
                                             const float* __restrict__ dinv,
                                             const unsigned* __restrict__ hWs,
                                             const float* __restrict__ bias,
                                             const int* __restrict__ batch,
                                             void* __restrict__ outp, int outBf,
                                             float* __restrict__ stats,
                                             float* __restrict__ praw,
                                             int N, int chunk,
                                             const float* __restrict__ gam,
                                             const float* __restrict__ bet,
                                             float* __restrict__ ss,
                                             const float* __restrict__ Wnext,
                                             unsigned* __restrict__ Wfb,
                                             float* __restrict__ cf,
                                             float invN, int* __restrict__ ticket) {
    int tid = threadIdx.x;
    int lane = tid & 63;
    int hf = lane >> 5;
    int m = lane & 31;
    int wid = blockIdx.x * 4 + (tid >> 6);
    int i0 = wid * chunk, i1 = min(i0 + chunk, N);
    float b0 = bias[2 * m], b1 = bias[2 * m + 1];
    float bs0 = 0.f, bs1 = 0.f, bq0 = 0.f, bq1 = 0.f;
    int curb = -1;
    float p0 = 0.f, p1 = 0.f;
    if (i0 < N) {
        int sb = rowp[i0];
        int send = rowp[i1];
        int i = i0;
        int rem = (rowp[i0 + 1] - sb) >> 4;
        float acc0 = 0.f, acc1 = 0.f;
        auto finalize = [&]() {
            float s0 = acc0 + __shfl_xor(acc0, 32);
            float s1 = acc1 + __shfl_xor(acc1, 32);
            float di = dinv[i];
            float h0 = fmaxf(fmaf(di, s0, b0), 0.f);
            float h1 = fmaxf(fmaf(di, s1, b1), 0.f);
            int b = batch[i];
            if (lane < 32) {
                if (outBf) ((unsigned*)outp)[(size_t)i * 32 + m] = tobf(h0) | (tobf(h1) << 16);
                else ((float2*)outp)[(size_t)i * 32 + m] = make_float2(h0, h1);
                bs0 += h0; bs1 += h1;
                bq0 = fmaf(h0, h0, bq0); bq1 = fmaf(h1, h1, bq1);
                if (b != curb) {
                    if (curb >= 0) {
                        atomicAdd(&praw[(size_t)curb * HD + 2 * m], p0);
                        atomicAdd(&praw[(size_t)curb * HD + 2 * m + 1], p1);
                    }
                    curb = b; p0 = h0; p1 = h1;
                } else { p0 += h0; p1 += h1; }
            }
            i++;
            rem = (i < i1) ? ((rowp[i + 1] - rowp[i]) >> 4) : 0x3fffffff;
            acc0 = 0.f; acc1 = 0.f;
        };
        for (; sb < send; sb += 64) {
            int eidx = ed[sb + lane];
            int ng = min(4, (send - sb) >> 4);
            if (ng == 4) {
                // full stage: issue all 32 gathers before consuming (deep MLP)
                unsigned u[32];
#pragma unroll
                for (int t = 0; t < 32; t++) {
                    int s = __shfl(eidx, 2 * t + hf);
                    u[t] = hWs[(size_t)s * 32 + m];
                }
#pragma unroll
                for (int g = 0; g < 4; g++) {
#pragma unroll
                    for (int jj = 0; jj < 8; jj++) {
                        acc0 += bf_lo(u[g * 8 + jj]);
                        acc1 += bf_hi(u[g * 8 + jj]);
                    }
                    if (--rem == 0) finalize();
                }
            } else {
                for (int g = 0; g < ng; g++) {
                    unsigned u[8];
#pragma unroll
                    for (int jj = 0; jj < 8; jj++) {
                        int s = __shfl(eidx, (g << 4) + 2 * jj + hf);
                        u[jj] = hWs[(size_t)s * 32 + m];
                    }
#pragma unroll
                    for (int jj = 0; jj < 8; jj++) {
                        acc0 += bf_lo(u[jj]);
                        acc1 += bf_hi(u[jj]);
                    }
                    if (--rem == 0) finalize();
                }
            }
        }
    }
    if (lane < 32 && curb >= 0) {
        atomicAdd(&praw[(size_t)curb * HD + 2 * m], p0);
        atomicAdd(&praw[(size_t)curb * HD + 2 * m + 1], p1);
    }
    __shared__ float r1s[4][HD], r2s[4][HD];
    int wv = tid >> 6;
    if (lane < 32) {
        r1s[wv][2 * m] = bs0; r1s[wv][2 * m + 1] = bs1;
        r2s[wv][2 * m] = bq0; r2s[wv][2 * m + 1] = bq1;
    }
    __syncthreads();
    if (tid < HD) {
        atomicAdd(&stats[tid], r1s[0][tid] + r1s[1][tid] + r1s[2][tid] + r1s[3][tid]);
        atomicAdd(&stats[HD + tid], r2s[0][tid] + r2s[1][tid] + r2s[2][tid] + r2s[3][tid]);
    }
    // ---- last block: BN finalize + fold into next layer's weights ----
    __shared__ int lastFlag;
    __syncthreads();
    if (tid == 0) {
        __threadfence();
        lastFlag = (atomicAdd(ticket, 1) == (int)gridDim.x - 1) ? 1 : 0;
    }
    __syncthreads();
    if (lastFlag) {
        __shared__ float lss[128];
        if (tid < HD) {
            float s1v = atomicAdd(&stats[tid], 0.f);
            float s2v = atomicAdd(&stats[HD + tid], 0.f);
            float mean = s1v * invN;
            float var = s2v * invN - mean * mean;
            float sc = gam[tid] * rsqrtf(var + BN_EPS);
            float sh = bet[tid] - mean * sc;
            ss[tid] = sc; ss[64 + tid] = sh;
            lss[tid] = sc; lss[64 + tid] = sh;
        }
        __syncthreads();
        if (Wnext && tid < HD) {
            float c = 0.f;
            for (int qq = 0; qq < 32; qq++) {
                float wa = Wnext[tid * HD + 2 * qq];
                float wb = Wnext[tid * HD + 2 * qq + 1];
                Wfb[tid * 32 + qq] = tobf(wa * lss[2 * qq]) | (tobf(wb * lss[2 * qq + 1]) << 16);
                c = fmaf(lss[64 + 2 * qq], wa, c);
                c = fmaf(lss[64 + 2 * qq + 1], wb, c);
            }
            cf[tid] = c;
        }
    }
}

// fused: normalize final h in place (float4) + pool finalize
__global__ __launch_bounds__(256) void k_fin(float* __restrict__ h,
                                             const float* __restrict__ ss_all,
                                             const float* __restrict__ praw,
                                             const int* __restrict__ cnt,
                                             float* __restrict__ pool,
                                             int nquads, int G) {
    int nb1 = (nquads + 255) >> 8;
    if ((int)blockIdx.x < nb1) {
        int idx = blockIdx.x * 256 + threadIdx.x;
        if (idx >= nquads) return;
        const float* ss = ss_all + 2 * 128;
        float4* h4 = (float4*)h;
        float4 v = h4[idx];
        int f0 = (idx * 4) & 63;
        v.x = fmaf(v.x, ss[f0 + 0], ss[64 + f0 + 0]);
        v.y = fmaf(v.y, ss[f0 + 1], ss[64 + f0 + 1]);
        v.z = fmaf(v.z, ss[f0 + 2], ss[64 + f0 + 2]);
        v.w = fmaf(v.w, ss[f0 + 3], ss[64 + f0 + 3]);
        h4[idx] = v;
    } else {
        int idx = (blockIdx.x - nb1) * 256 + threadIdx.x;
        if (idx >= G * 192) return;
        int g = idx / 192;
        int r = idx - g * 192;
        int l = r >> 6;
        int f = r & 63;
        const float* ss = ss_all + l * 128;
        float v = praw[((size_t)l * G + g) * HD + f];
        pool[idx] = fmaf(ss[f], v, (float)cnt[g] * ss[64 + f]);
    }
}

extern "C" void kernel_launch(void* const* d_in, const int* in_sizes, int n_in,
                              void* d_out, int out_size, void* d_ws, size_t ws_size,
                              hipStream_t stream) {
    const int N = in_sizes[0] / HD;             // 100000
    const int E = in_sizes[1] / 2;              // 1000000
    const int G = (out_size - N * HD) / 192;    // 512

    const float* x = (const float*)d_in[0];
    const int* ei = (const int*)d_in[1];
    const int* srcA = ei;
    const int* dstA = ei + E;
    const int* batch = (const int*)d_in[2];
    const float* W[3]    = {(const float*)d_in[3], (const float*)d_in[7],  (const float*)d_in[11]};
    const float* bias[3] = {(const float*)d_in[4], (const float*)d_in[8],  (const float*)d_in[12]};
    const float* gam[3]  = {(const float*)d_in[5], (const float*)d_in[9],  (const float*)d_in[13]};
    const float* bet[3]  = {(const float*)d_in[6], (const float*)d_in[10], (const float*)d_in[14]};

    char* ws = (char*)d_ws;
    size_t off = 0;
    auto alloc = [&](size_t bytes) -> void* {
        void* p = ws + off;
        off = (off + bytes + 255) & ~(size_t)255;
        return p;
    };
    // zero-region (single memset): deg, cur, stats, tickets, praw
    int* deg     = (int*)alloc((size_t)N * 4);
    int* cur     = (int*)alloc((size_t)N * 4);
    float* stats = (float*)alloc(3 * 128 * 4);
    int* tickets = (int*)alloc(3 * 4);
    float* praw  = (float*)alloc((size_t)3 * G * HD * 4);
    size_t zbytes = off;
    float* dinv  = (float*)alloc((size_t)N * 4);
    int* rowp    = (int*)alloc((size_t)(N + 1) * 4);
    int* incl    = (int*)alloc((size_t)N * 4);
    int* bsums   = (int*)alloc(512 * 4);
    int* ed      = (int*)alloc(((size_t)E + 16 * (size_t)N) * 4 + 512);
    unsigned short* hWs  = (unsigned short*)alloc((size_t)(N + 1) * HD * 2);
    unsigned short* hraw = (unsigned short*)alloc((size_t)N * HD * 2);
    float* ss    = (float*)alloc(3 * 128 * 4);
    unsigned* Wfb = (unsigned*)alloc(2 * HD * 32 * 4);
    float* cf    = (float*)alloc(2 * HD * 4);
    int* gcnt    = (int*)alloc((size_t)G * 4);
    (void)ws_size;

    float* pool = (float*)d_out;                      // [G,192]
    float* hbuf = (float*)d_out + (size_t)G * 192;    // [N,64] final h (fp32)

    hipMemsetAsync(deg, 0, zbytes, stream);

    int nb = (N + 255) / 256;
    k_deg<<<(E + 255) / 256, 256, 0, stream>>>(dstA, deg, E);
    k_scan1<<<nb, 256, 0, stream>>>(deg, incl, bsums, dinv, (unsigned*)hWs, N);
    k_scan3<<<nb, 256, 0, stream>>>(rowp, deg, incl, bsums, ed, N, nb);
    k_fill<<<(E + 255) / 256, 256, 0, stream>>>(srcA, dstA, rowp, cur, ed, batch, gcnt, E, N, G);

    const int AGG_BLOCKS = NWAVES / 4;
    const int chunk = (N + NWAVES - 1) / NWAVES;
    const int ntiles = (N + 15) / 16;

    for (int l = 0; l < 3; l++) {
        if (l == 0)
            k_gemm2<1><<<640, 256, 0, stream>>>(x, W[0], nullptr, dinv, hWs, N, ntiles);
        else
            k_gemm2<0><<<640, 256, 0, stream>>>(hraw, Wfb + (size_t)(l - 1) * HD * 32,
                                                cf + (l - 1) * HD, dinv, hWs, N, ntiles);
        void* outp = (l < 2) ? (void*)hraw : (void*)hbuf;
        k_agg<<<AGG_BLOCKS, 256, 0, stream>>>(rowp, ed, dinv, (const unsigned*)hWs,
                                              bias[l], batch, outp, (l < 2) ? 1 : 0,
                                              stats + l * 128, praw + (size_t)l * G * HD,
                                              N, chunk,
                                              gam[l], bet[l], ss + l * 128,
                                              (l < 2) ? W[l + 1] : nullptr,
                                              Wfb + (size_t)(l < 2 ? l : 0) * HD * 32,
                                              cf + (l < 2 ? l : 0) * HD,
                                              1.0f / (float)N, tickets + l);
    }
    int nquads = N * HD / 4;
    int nb1 = (nquads + 255) / 256;
    int nb2 = (G * 192 + 255) / 256;
    k_fin<<<nb1 + nb2, 256, 0, stream>>>(hbuf, ss, praw, gcnt, pool, nquads, G);
}